// Round 9
// baseline (8011.593 us; speedup 1.0000x reference)
//
#include <hip/hip_runtime.h>

typedef unsigned short u16;
typedef unsigned int   u32;
typedef __attribute__((ext_vector_type(4))) unsigned int au4;
typedef __attribute__((ext_vector_type(4))) float fx4;
typedef __attribute__((ext_vector_type(8))) __bf16 bf16x8;

#define NTHREADS 512
#define NBLOCKS  256
#define BB       2
#define STEPS    1024
#define TPTS     1025
#define HDIM     64
#define NZ       16
#define WID      128
#define IND      65
#define HN       1024

__device__ __forceinline__ float bf2f(u16 v) { return __uint_as_float(((u32)v) << 16); }
__device__ __forceinline__ u16 f2bf(float f) {
    u32 u = __float_as_uint(f);
    return (u16)((u + 0x7fffu + ((u >> 16) & 1u)) >> 16);
}
__device__ __forceinline__ float lo16(u32 u) { return __uint_as_float(u << 16); }
__device__ __forceinline__ float hi16(u32 u) { return __uint_as_float(u & 0xffff0000u); }
__device__ __forceinline__ u32 pk(float a, float b) {
    return (u32)f2bf(a) | ((u32)f2bf(b) << 16);
}

// AGPR pinning (validated R6-R8): "=a" def homes weight fragments in AGPRs so
// the scheduler can't sink the global loads into the loop; ageta keeps them in
// the 'a' class so MFMA consumes AGPR operands directly.
__device__ __forceinline__ au4 apin(uint4 v) {
    au4 t; t.x = v.x; t.y = v.y; t.z = v.z; t.w = v.w;
    au4 r;
    asm volatile("" : "=a"(r) : "0"(t));
    return r;
}
__device__ __forceinline__ au4 ageta(au4 a) {
    au4 t;
    asm volatile("" : "=a"(t) : "0"(a));
    return t;
}

template <bool IS32>
__device__ __forceinline__ float ldf(const void* p, int i) {
    return IS32 ? ((const float*)p)[i] : bf2f(((const u16*)p)[i]);
}
template <bool IS32>
__device__ __forceinline__ u16 ldbf(const void* p, int i) {
    return IS32 ? f2bf(((const float*)p)[i]) : ((const u16*)p)[i];
}

__device__ __forceinline__ float rcpf(float x) { return __builtin_amdgcn_rcpf(x); }
__device__ __forceinline__ float lipswish(float x) {
    return 0.909f * x * rcpf(1.0f + __expf(-x));   // inf-safe: rcp(inf)=0
}
__device__ __forceinline__ float tanh_fast(float x) {
    float e = __expf(2.0f * fabsf(x));
    float t = 1.0f - 2.0f * rcpf(e + 1.0f);
    return copysignf(t, x);
}
__device__ __forceinline__ void split_bf(float v, u16& hi, u16& lo) {
    hi = f2bf(v);
    lo = f2bf(v - bf2f(hi));
}

struct __align__(16) SMem {
    // activations as MFMA B operands: bf16 hi + lo residual
    __align__(16) u16 bxh[BB][96],  bxl[BB][96];        // x=[t,y,pad]
    __align__(16) u16 bh1h[2][BB][WID], bh1l[2][BB][WID];
    __align__(16) u16 bh2vh[BB][WID], bh2vl[BB][WID];
    __align__(16) u16 bh2ch[BB][WID], bh2cl[BB][WID];
    __align__(16) u16 vW2F[4][4][64][8];                // drift L2, frag-major
    // big-layer raw accumulators: H = A*Bhi (cols 0,1), L = A*Blo (cols 2,3)
    __align__(16) float accBH[BB][HN], accBL[BB][HN];
    __align__(16) float b0s[256], b1s[256], vb2[HDIM], vsc[HDIM];
    __align__(16) float cb2[HN], csc[HN];
    __align__(16) float roW[8][HDIM];
    __align__(16) float rob[8];
    __align__(16) float tsb[1028];
    __align__(16) float yb[BB][HDIM], g0b[BB][HDIM], fdt[BB][HDIM];
    __align__(16) float dwb[BB][NZ];
};

__device__ __forceinline__ bf16x8 bfrag(const u16* p) {
    return __builtin_bit_cast(bf16x8, *(const uint4*)p);
}
__device__ __forceinline__ fx4 mf1(au4 a, bf16x8 b, fx4 acc) {
    bf16x8 af = __builtin_bit_cast(bf16x8, ageta(a));
    return __builtin_amdgcn_mfma_f32_16x16x32_bf16(af, b, acc, 0, 0, 0);
}
__device__ __forceinline__ fx4 shflx2(fx4 v) {
    fx4 r;
    r.x = __shfl_xor(v.x, 2); r.y = __shfl_xor(v.y, 2);
    r.z = __shfl_xor(v.z, 2); r.w = __shfl_xor(v.w, 2);
    return r;
}
// lipswish + bf16 hi/lo split + packed b64 stores for 4 consecutive rows
__device__ __forceinline__ void act_store4(u16* dh, u16* dl, fx4 pre) {
    fx4 h;
    h.x = lipswish(pre.x); h.y = lipswish(pre.y);
    h.z = lipswish(pre.z); h.w = lipswish(pre.w);
    u16 a0 = f2bf(h.x), a1 = f2bf(h.y), a2 = f2bf(h.z), a3 = f2bf(h.w);
    uint2 H; H.x = (u32)a0 | ((u32)a1 << 16); H.y = (u32)a2 | ((u32)a3 << 16);
    u16 l0 = f2bf(h.x - bf2f(a0)), l1 = f2bf(h.y - bf2f(a1));
    u16 l2 = f2bf(h.z - bf2f(a2)), l3 = f2bf(h.w - bf2f(a3));
    uint2 L; L.x = (u32)l0 | ((u32)l1 << 16); L.y = (u32)l2 | ((u32)l3 << 16);
    *(uint2*)dh = H;
    *(uint2*)dl = L;
}

template <bool IS32>
__device__ __forceinline__ uint4 load8(const void* src, int row, int stride, int k0, int Klim) {
    u16 e[8];
    #pragma unroll
    for (int j = 0; j < 8; ++j) {
        int k = k0 + j;
        e[j] = (k < Klim) ? ldbf<IS32>(src, row * stride + k) : (u16)0;
    }
    uint4 v;
    v.x = (u32)e[0] | ((u32)e[1] << 16);
    v.y = (u32)e[2] | ((u32)e[3] << 16);
    v.z = (u32)e[4] | ((u32)e[5] << 16);
    v.w = (u32)e[6] | ((u32)e[7] << 16);
    return v;
}

template <bool IS32>
__device__ __forceinline__ void stage_dw(SMem& sm, const uint4& d, int q, float sdt) {
    if (IS32) {
        const float* pf = (const float*)&d;
        int f = q * 4;
        #pragma unroll
        for (int k = 0; k < 4; ++k)
            sm.dwb[(f + k) >> 4][(f + k) & 15] = pf[k] * sdt;
    } else {
        int f = q * 8;
        u32 u0 = d.x, u1 = d.y, u2 = d.z, u3 = d.w;
        sm.dwb[(f    ) >> 4][(f    ) & 15] = lo16(u0) * sdt;
        sm.dwb[(f + 1) >> 4][(f + 1) & 15] = hi16(u0) * sdt;
        sm.dwb[(f + 2) >> 4][(f + 2) & 15] = lo16(u1) * sdt;
        sm.dwb[(f + 3) >> 4][(f + 3) & 15] = hi16(u1) * sdt;
        sm.dwb[(f + 4) >> 4][(f + 4) & 15] = lo16(u2) * sdt;
        sm.dwb[(f + 5) >> 4][(f + 5) & 15] = hi16(u2) * sdt;
        sm.dwb[(f + 6) >> 4][(f + 6) & 15] = lo16(u3) * sdt;
        sm.dwb[(f + 7) >> 4][(f + 7) & 15] = hi16(u3) * sdt;
    }
}

template <bool IS32>
__device__ __forceinline__ void write_out(void* out, size_t idx, const float* v8) {
    if (IS32) {
        float4 o0, o1;
        o0.x = v8[0]; o0.y = v8[1]; o0.z = v8[2]; o0.w = v8[3];
        o1.x = v8[4]; o1.y = v8[5]; o1.z = v8[6]; o1.w = v8[7];
        ((float4*)out)[idx * 2]     = o0;
        ((float4*)out)[idx * 2 + 1] = o1;
    } else {
        uint4 o;
        o.x = pk(v8[0], v8[1]);
        o.y = pk(v8[2], v8[3]);
        o.z = pk(v8[4], v8[5]);
        o.w = pk(v8[6], v8[7]);
        ((uint4*)out)[idx] = o;
    }
}

template <bool IS32>
__device__ __forceinline__ void
sde_run(SMem& sm,
        const void* ts,  const void* z0,  const void* dW,
        const void* iW0, const void* ib0, const void* iW1, const void* ib1,
        const void* iW2, const void* ib2,
        const void* vW0, const void* vb0, const void* vW1, const void* vb1,
        const void* vW2, const void* vb2, const void* vsc,
        const void* cW0, const void* cb0, const void* cW1, const void* cb1,
        const void* cW2, const void* cb2, const void* csc,
        const void* roW, const void* rob, void* out,
        int tid, int bid)
{
    const int lane = tid & 63, wv = tid >> 6;
    const int mm = lane & 15, qq = lane >> 4;
    const int nn = mm;                 // B/D column within tile
    const int smp = nn & 1;            // sample this column carries
    const int prt = (nn >> 1) & 1;     // 0 = hi part, 1 = lo part

    // ---- weight A-fragments -> AGPRs (184 u32/thread) ----
    au4 a0[6];    // stacked [vW0;cW0] rows 16(2wv+rtl)+mm, kt 0..2 (K=65 pad 96)
    au4 a1[8];    // waves0-3 vW1, waves4-7 cW1: rows 16(2(wv&3)+rtl)+mm, kt 0..3
    au4 ab[32];   // cW2: rows 128wv+16r8+mm, kt 0..3
    #pragma unroll
    for (int rtl = 0; rtl < 2; ++rtl) {
        int grow = 16 * (2 * wv + rtl) + mm;
        const void* src = (grow < 128) ? vW0 : cW0;
        int r = grow & 127;
        #pragma unroll
        for (int kt = 0; kt < 3; ++kt)
            a0[rtl * 3 + kt] = apin(load8<IS32>(src, r, IND, 32 * kt + 8 * qq, IND));
    }
    {
        const void* src = (wv < 4) ? vW1 : cW1;
        int wl = wv & 3;
        #pragma unroll
        for (int rtl = 0; rtl < 2; ++rtl) {
            int r = 16 * (2 * wl + rtl) + mm;
            #pragma unroll
            for (int kt = 0; kt < 4; ++kt)
                a1[rtl * 4 + kt] = apin(load8<IS32>(src, r, WID, 32 * kt + 8 * qq, WID));
        }
    }
    #pragma unroll
    for (int r8 = 0; r8 < 8; ++r8) {
        int r = 128 * wv + 16 * r8 + mm;
        #pragma unroll
        for (int kt = 0; kt < 4; ++kt)
            ab[r8 * 4 + kt] = apin(load8<IS32>(cW2, r, WID, 32 * kt + 8 * qq, WID));
    }

    // ---- LDS staging ----
    for (int slot = tid; slot < 1024; slot += NTHREADS) {
        int rt = slot >> 8, kt = (slot >> 6) & 3, l = slot & 63;
        int m = l & 15, q = l >> 4;
        uint4 v = load8<IS32>(vW2, 16 * rt + m, WID, 32 * kt + 8 * q, WID);
        *(uint4*)&sm.vW2F[rt][kt][l][0] = v;
    }
    if (tid < 256) {
        sm.b0s[tid] = (tid < 128) ? ldf<IS32>(vb0, tid) : ldf<IS32>(cb0, tid - 128);
        sm.b1s[tid] = (tid < 128) ? ldf<IS32>(vb1, tid) : ldf<IS32>(cb1, tid - 128);
    } else if (tid < 320) {
        int i = tid - 256;
        sm.vb2[i] = ldf<IS32>(vb2, i);
        sm.vsc[i] = ldf<IS32>(vsc, i);
    } else if (tid < 328) {
        sm.rob[tid - 320] = ldf<IS32>(rob, tid - 320);
    } else if (tid >= 384 && tid < 448) {
        int b = (tid - 384) >> 5, k = 65 + ((tid - 384) & 31);
        if (k < 96) { sm.bxh[b][k] = 0; sm.bxl[b][k] = 0; }
    }
    for (int i = tid; i < HN; i += NTHREADS) {
        sm.cb2[i] = ldf<IS32>(cb2, i);
        sm.csc[i] = ldf<IS32>(csc, i);
    }
    { int d = tid >> 6, i2 = tid & 63; sm.roW[d][i2] = ldf<IS32>(roW, tid); }
    for (int i = tid; i < TPTS; i += NTHREADS) sm.tsb[i] = ldf<IS32>(ts, i);

    uint4 dwpref;
    if (tid >= 128 && tid < 136) {
        int q = tid - 128;
        if (IS32)       dwpref = ((const uint4*)dW)[(size_t)bid * 8 + q];
        else if (q < 4) dwpref = ((const uint4*)dW)[(size_t)bid * 4 + q];
    }
    __syncthreads();

    const float dt  = sm.tsb[1] - sm.tsb[0];
    const float sdt = sqrtf(dt);
    if (tid >= 128 && tid < 136) {
        int q = tid - 128;
        if (IS32 || q < 4) stage_dw<IS32>(sm, dwpref, q, sdt);
    }

    // ---- initial MLP (VALU, once): z0 -> 128 -> 128 -> y0; scratch in accBH/accBL ----
    if (tid < 256) {
        int b = tid >> 7, j = tid & 127;
        float acc = ldf<IS32>(ib0, j);
        #pragma unroll
        for (int k = 0; k < 8; ++k)
            acc = fmaf(ldf<IS32>(iW0, j * 8 + k), ldf<IS32>(z0, (bid * BB + b) * 8 + k), acc);
        sm.accBH[b][j] = fmaxf(acc, 0.0f);
    }
    __syncthreads();
    if (tid < 256) {
        int b = tid >> 7, j = tid & 127;
        float acc = ldf<IS32>(ib1, j);
        for (int k = 0; k < WID; ++k)
            acc = fmaf(ldf<IS32>(iW1, j * WID + k), sm.accBH[b][k], acc);
        sm.accBL[b][j] = fmaxf(acc, 0.0f);
    }
    __syncthreads();
    if (tid < 128) {
        int b = tid >> 6, i = tid & 63;
        float y0 = ldf<IS32>(ib2, i);
        for (int k = 0; k < WID; ++k)
            y0 = fmaf(ldf<IS32>(iW2, i * WID + k), sm.accBL[b][k], y0);
        sm.yb[b][i] = y0;
        u16 hi, lo; split_bf(y0, hi, lo);
        sm.bxh[b][1 + i] = hi; sm.bxl[b][1 + i] = lo;
        if (i == 0) {
            u16 thi, tlo; split_bf(sm.tsb[0], thi, tlo);
            sm.bxh[b][0] = thi; sm.bxl[b][0] = tlo;
        }
    }
    __syncthreads();

    // ---- main scan: 8 barriers/step ----
    for (int s = 0; s < STEPS; ++s) {
        // PA: L0 both MLPs on x (all waves), inline act -> bh1; stage dwb (s>0)
        if (s > 0 && tid >= 128 && tid < 136) {
            int q = tid - 128;
            if (IS32 || q < 4) stage_dw<IS32>(sm, dwpref, q, sdt);
        }
        {
            const u16* xs = prt ? &sm.bxl[smp][0] : &sm.bxh[smp][0];
            bf16x8 bx[3];
            #pragma unroll
            for (int kt = 0; kt < 3; ++kt) bx[kt] = bfrag(&xs[32 * kt + 8 * qq]);
            #pragma unroll
            for (int rtl = 0; rtl < 2; ++rtl) {
                fx4 acc = {0.f, 0.f, 0.f, 0.f};
                #pragma unroll
                for (int kt = 0; kt < 3; ++kt) acc = mf1(a0[rtl * 3 + kt], bx[kt], acc);
                int rowb = 16 * (2 * wv + rtl) + 4 * qq;
                fx4 lo4 = shflx2(acc);
                if (nn < 2) {
                    float4 bs = *(const float4*)&sm.b0s[rowb];
                    fx4 pre;
                    pre.x = acc.x + lo4.x + bs.x; pre.y = acc.y + lo4.y + bs.y;
                    pre.z = acc.z + lo4.z + bs.z; pre.w = acc.w + lo4.w + bs.w;
                    int mlp = rowb >> 7, j0 = rowb & 127;
                    act_store4(&sm.bh1h[mlp][nn][j0], &sm.bh1l[mlp][nn][j0], pre);
                }
            }
        }
        __syncthreads();
        // PB: L1 (waves0-3 drift, 4-7 diffusion), inline act -> bh2v / bh2c
        {
            int mlp = (wv < 4) ? 0 : 1, wl = wv & 3;
            const u16* hs = prt ? &sm.bh1l[mlp][smp][0] : &sm.bh1h[mlp][smp][0];
            bf16x8 bf[4];
            #pragma unroll
            for (int kt = 0; kt < 4; ++kt) bf[kt] = bfrag(&hs[32 * kt + 8 * qq]);
            #pragma unroll
            for (int rtl = 0; rtl < 2; ++rtl) {
                fx4 acc = {0.f, 0.f, 0.f, 0.f};
                #pragma unroll
                for (int kt = 0; kt < 4; ++kt) acc = mf1(a1[rtl * 4 + kt], bf[kt], acc);
                int rowb = 16 * (2 * wl + rtl) + 4 * qq;
                fx4 lo4 = shflx2(acc);
                if (nn < 2) {
                    float4 bs = *(const float4*)&sm.b1s[mlp * 128 + rowb];
                    fx4 pre;
                    pre.x = acc.x + lo4.x + bs.x; pre.y = acc.y + lo4.y + bs.y;
                    pre.z = acc.z + lo4.z + bs.z; pre.w = acc.w + lo4.w + bs.w;
                    if (mlp == 0) act_store4(&sm.bh2vh[nn][rowb], &sm.bh2vl[nn][rowb], pre);
                    else          act_store4(&sm.bh2ch[nn][rowb], &sm.bh2cl[nn][rowb], pre);
                }
            }
        }
        __syncthreads();
        // PC: big MFMA eval1 (all waves) -> accBH/accBL; drift L2 inline -> fdt (waves 0-3)
        {
            const u16* cs2 = prt ? &sm.bh2cl[smp][0] : &sm.bh2ch[smp][0];
            bf16x8 bc[4];
            #pragma unroll
            for (int kt = 0; kt < 4; ++kt) bc[kt] = bfrag(&cs2[32 * kt + 8 * qq]);
            #pragma unroll
            for (int r8 = 0; r8 < 8; ++r8) {
                fx4 acc = {0.f, 0.f, 0.f, 0.f};
                #pragma unroll
                for (int kt = 0; kt < 4; ++kt) acc = mf1(ab[r8 * 4 + kt], bc[kt], acc);
                int rowb = 128 * wv + 16 * r8 + 4 * qq;
                if (nn < 2)      *(fx4*)&sm.accBH[nn][rowb] = acc;
                else if (nn < 4) *(fx4*)&sm.accBL[nn - 2][rowb] = acc;
            }
            if (wv < 4) {
                const u16* vs2 = prt ? &sm.bh2vl[smp][0] : &sm.bh2vh[smp][0];
                fx4 acc = {0.f, 0.f, 0.f, 0.f};
                #pragma unroll
                for (int kt = 0; kt < 4; ++kt) {
                    bf16x8 aw = bfrag(&sm.vW2F[wv][kt][lane][0]);
                    acc = __builtin_amdgcn_mfma_f32_16x16x32_bf16(aw, bfrag(&vs2[32 * kt + 8 * qq]), acc, 0, 0, 0);
                }
                fx4 lo4 = shflx2(acc);
                if (nn < 2) {
                    int i0 = 16 * wv + 4 * qq;
                    float4 vb = *(const float4*)&sm.vb2[i0];
                    float4 vs = *(const float4*)&sm.vsc[i0];
                    float4 o;
                    o.x = vs.x * tanh_fast(acc.x + lo4.x + vb.x) * dt;
                    o.y = vs.y * tanh_fast(acc.y + lo4.y + vb.y) * dt;
                    o.z = vs.z * tanh_fast(acc.z + lo4.z + vb.z) * dt;
                    o.w = vs.w * tanh_fast(acc.w + lo4.w + vb.w) * dt;
                    *(float4*)&sm.fdt[nn][i0] = o;
                }
            }
        }
        __syncthreads();
        // PD: big epilogue 1 (512 thr): g0; q4==0 lanes: g0b store + x' pack
        {
            int b = tid >> 8, h = (tid >> 2) & 63, q4 = tid & 3;
            int rb = 16 * h + 4 * q4;
            fx4 aH = *(const fx4*)&sm.accBH[b][rb];
            fx4 aL = *(const fx4*)&sm.accBL[b][rb];
            float4 cb = *(const float4*)&sm.cb2[rb];
            float4 cs = *(const float4*)&sm.csc[rb];
            float4 dw = *(const float4*)&sm.dwb[b][4 * q4];
            float v;
            v  = tanh_fast(aH.x + aL.x + cb.x) * cs.x * dw.x;
            v  = fmaf(tanh_fast(aH.y + aL.y + cb.y) * cs.y, dw.y, v);
            v  = fmaf(tanh_fast(aH.z + aL.z + cb.z) * cs.z, dw.z, v);
            v  = fmaf(tanh_fast(aH.w + aL.w + cb.w) * cs.w, dw.w, v);
            v += __shfl_xor(v, 1);
            v += __shfl_xor(v, 2);
            if (q4 == 0) {
                sm.g0b[b][h] = v;
                float xp = sm.yb[b][h] + v;
                u16 hi, lo; split_bf(xp, hi, lo);
                sm.bxh[b][1 + h] = hi; sm.bxl[b][1 + h] = lo;
            }
        }
        __syncthreads();
        // PE: diffusion L0 on x' (waves 4-7) | readout y_s (tid<128) | dW prefetch
        if (wv >= 4) {
            const u16* xs = prt ? &sm.bxl[smp][0] : &sm.bxh[smp][0];
            bf16x8 bx[3];
            #pragma unroll
            for (int kt = 0; kt < 3; ++kt) bx[kt] = bfrag(&xs[32 * kt + 8 * qq]);
            #pragma unroll
            for (int rtl = 0; rtl < 2; ++rtl) {
                fx4 acc = {0.f, 0.f, 0.f, 0.f};
                #pragma unroll
                for (int kt = 0; kt < 3; ++kt) acc = mf1(a0[rtl * 3 + kt], bx[kt], acc);
                int rowb = 16 * (2 * wv + rtl) + 4 * qq;   // 128..255
                fx4 lo4 = shflx2(acc);
                if (nn < 2) {
                    float4 bs = *(const float4*)&sm.b0s[rowb];
                    fx4 pre;
                    pre.x = acc.x + lo4.x + bs.x; pre.y = acc.y + lo4.y + bs.y;
                    pre.z = acc.z + lo4.z + bs.z; pre.w = acc.w + lo4.w + bs.w;
                    int j0 = rowb & 127;
                    act_store4(&sm.bh1h[1][nn][j0], &sm.bh1l[1][nn][j0], pre);
                }
            }
        } else if (tid < 128) {
            int b = tid >> 6, i = tid & 63;
            float y = sm.yb[b][i];
            float acc8[8];
            #pragma unroll
            for (int d = 0; d < 8; ++d) acc8[d] = sm.roW[d][i] * y;
            #pragma unroll
            for (int m = 1; m < 64; m <<= 1) {
                #pragma unroll
                for (int d = 0; d < 8; ++d) acc8[d] += __shfl_xor(acc8[d], m);
            }
            if (i == 0) {
                float v8[8];
                #pragma unroll
                for (int d = 0; d < 8; ++d) v8[d] = acc8[d] + sm.rob[d];
                write_out<IS32>(out, (size_t)(bid * BB + b) * TPTS + s, v8);
            }
        } else if (tid >= 128 && tid < 136 && s + 1 < STEPS) {
            int q = tid - 128;
            if (IS32)       dwpref = ((const uint4*)dW)[(size_t)(s + 1) * 2048 + bid * 8 + q];
            else if (q < 4) dwpref = ((const uint4*)dW)[(size_t)(s + 1) * 1024 + bid * 4 + q];
        }
        __syncthreads();
        // PF: diffusion L1 (waves 4-7), inline act -> bh2c
        if (wv >= 4) {
            int wl = wv & 3;
            const u16* hs = prt ? &sm.bh1l[1][smp][0] : &sm.bh1h[1][smp][0];
            bf16x8 bf[4];
            #pragma unroll
            for (int kt = 0; kt < 4; ++kt) bf[kt] = bfrag(&hs[32 * kt + 8 * qq]);
            #pragma unroll
            for (int rtl = 0; rtl < 2; ++rtl) {
                fx4 acc = {0.f, 0.f, 0.f, 0.f};
                #pragma unroll
                for (int kt = 0; kt < 4; ++kt) acc = mf1(a1[rtl * 4 + kt], bf[kt], acc);
                int rowb = 16 * (2 * wl + rtl) + 4 * qq;
                fx4 lo4 = shflx2(acc);
                if (nn < 2) {
                    float4 bs = *(const float4*)&sm.b1s[128 + rowb];
                    fx4 pre;
                    pre.x = acc.x + lo4.x + bs.x; pre.y = acc.y + lo4.y + bs.y;
                    pre.z = acc.z + lo4.z + bs.z; pre.w = acc.w + lo4.w + bs.w;
                    act_store4(&sm.bh2ch[nn][rowb], &sm.bh2cl[nn][rowb], pre);
                }
            }
        }
        __syncthreads();
        // PG: big MFMA eval2 (all waves) -> accBH/accBL
        {
            const u16* cs2 = prt ? &sm.bh2cl[smp][0] : &sm.bh2ch[smp][0];
            bf16x8 bc[4];
            #pragma unroll
            for (int kt = 0; kt < 4; ++kt) bc[kt] = bfrag(&cs2[32 * kt + 8 * qq]);
            #pragma unroll
            for (int r8 = 0; r8 < 8; ++r8) {
                fx4 acc = {0.f, 0.f, 0.f, 0.f};
                #pragma unroll
                for (int kt = 0; kt < 4; ++kt) acc = mf1(ab[r8 * 4 + kt], bc[kt], acc);
                int rowb = 128 * wv + 16 * r8 + 4 * qq;
                if (nn < 2)      *(fx4*)&sm.accBH[nn][rowb] = acc;
                else if (nn < 4) *(fx4*)&sm.accBL[nn - 2][rowb] = acc;
            }
        }
        __syncthreads();
        // PH: big epilogue 2 (512 thr): g1; q4==0: y1 update + next-x pack + t
        {
            int b = tid >> 8, h = (tid >> 2) & 63, q4 = tid & 3;
            int rb = 16 * h + 4 * q4;
            fx4 aH = *(const fx4*)&sm.accBH[b][rb];
            fx4 aL = *(const fx4*)&sm.accBL[b][rb];
            float4 cb = *(const float4*)&sm.cb2[rb];
            float4 cs = *(const float4*)&sm.csc[rb];
            float4 dw = *(const float4*)&sm.dwb[b][4 * q4];
            float v;
            v  = tanh_fast(aH.x + aL.x + cb.x) * cs.x * dw.x;
            v  = fmaf(tanh_fast(aH.y + aL.y + cb.y) * cs.y, dw.y, v);
            v  = fmaf(tanh_fast(aH.z + aL.z + cb.z) * cs.z, dw.z, v);
            v  = fmaf(tanh_fast(aH.w + aL.w + cb.w) * cs.w, dw.w, v);
            v += __shfl_xor(v, 1);
            v += __shfl_xor(v, 2);
            if (q4 == 0) {
                float y1 = sm.yb[b][h] + sm.fdt[b][h] + 0.5f * (sm.g0b[b][h] + v);
                sm.yb[b][h] = y1;
                u16 hi, lo; split_bf(y1, hi, lo);
                sm.bxh[b][1 + h] = hi; sm.bxl[b][1 + h] = lo;
                if (h == 0) {
                    u16 thi, tlo; split_bf(sm.tsb[s + 1], thi, tlo);
                    sm.bxh[b][0] = thi; sm.bxl[b][0] = tlo;
                }
            }
        }
        __syncthreads();
    }

    // final readout: y_1024
    if (tid < 128) {
        int b = tid >> 6, i = tid & 63;
        float y = sm.yb[b][i];
        float acc8[8];
        #pragma unroll
        for (int d = 0; d < 8; ++d) acc8[d] = sm.roW[d][i] * y;
        #pragma unroll
        for (int m = 1; m < 64; m <<= 1) {
            #pragma unroll
            for (int d = 0; d < 8; ++d) acc8[d] += __shfl_xor(acc8[d], m);
        }
        if (i == 0) {
            float v8[8];
            #pragma unroll
            for (int d = 0; d < 8; ++d) v8[d] = acc8[d] + sm.rob[d];
            write_out<IS32>(out, (size_t)(bid * BB + b) * TPTS + STEPS, v8);
        }
    }
}

__global__ void
__attribute__((amdgpu_flat_work_group_size(NTHREADS, NTHREADS), amdgpu_waves_per_eu(2, 2)))
sde_kernel(const void* __restrict__ ts,  const void* __restrict__ z0,  const void* __restrict__ dW,
           const void* __restrict__ iW0, const void* __restrict__ ib0, const void* __restrict__ iW1,
           const void* __restrict__ ib1, const void* __restrict__ iW2, const void* __restrict__ ib2,
           const void* __restrict__ vW0, const void* __restrict__ vb0, const void* __restrict__ vW1,
           const void* __restrict__ vb1, const void* __restrict__ vW2, const void* __restrict__ vb2,
           const void* __restrict__ vsc, const void* __restrict__ cW0, const void* __restrict__ cb0,
           const void* __restrict__ cW1, const void* __restrict__ cb1, const void* __restrict__ cW2,
           const void* __restrict__ cb2, const void* __restrict__ csc, const void* __restrict__ roW,
           const void* __restrict__ rob, void* __restrict__ out)
{
    __shared__ SMem sm;
    const int tid = threadIdx.x;
    const int bid = blockIdx.x;

    // dtype detection: u16 word #1 of ts (bf16 -> 0x3A80 != 0; fp32 -> 0)
    const bool is32 = (((const u16*)ts)[1] == 0);

    if (is32) {
        sde_run<true>(sm, ts, z0, dW, iW0, ib0, iW1, ib1, iW2, ib2,
                      vW0, vb0, vW1, vb1, vW2, vb2, vsc,
                      cW0, cb0, cW1, cb1, cW2, cb2, csc, roW, rob, out, tid, bid);
    } else {
        sde_run<false>(sm, ts, z0, dW, iW0, ib0, iW1, ib1, iW2, ib2,
                       vW0, vb0, vW1, vb1, vW2, vb2, vsc,
                       cW0, cb0, cW1, cb1, cW2, cb2, csc, roW, rob, out, tid, bid);
    }
}

extern "C" void kernel_launch(void* const* d_in, const int* in_sizes, int n_in,
                              void* d_out, int out_size, void* d_ws, size_t ws_size,
                              hipStream_t stream) {
    (void)in_sizes; (void)n_in; (void)d_ws; (void)ws_size; (void)out_size;
    hipLaunchKernelGGL(sde_kernel, dim3(NBLOCKS), dim3(NTHREADS), 0, stream,
                       d_in[0], d_in[1], d_in[2], d_in[3], d_in[4], d_in[5], d_in[6],
                       d_in[7], d_in[8], d_in[9], d_in[10], d_in[11], d_in[12], d_in[13],
                       d_in[14], d_in[15], d_in[16], d_in[17], d_in[18], d_in[19], d_in[20],
                       d_in[21], d_in[22], d_in[23], d_in[24], d_out);
}

// Round 10
// 5888.189 us; speedup vs baseline: 1.3606x; 1.3606x over previous
//
#include <hip/hip_runtime.h>

typedef unsigned short u16;
typedef unsigned int   u32;
typedef __attribute__((ext_vector_type(4))) unsigned int au4;
typedef __attribute__((ext_vector_type(4))) float fx4;
typedef __attribute__((ext_vector_type(8))) __bf16 bf16x8;

#define NTHREADS 512
#define NBLOCKS  256
#define BB       2
#define STEPS    1024
#define TPTS     1025
#define HDIM     64
#define NZ       16
#define WID      128
#define IND      65
#define HN       1024

__device__ __forceinline__ float bf2f(u16 v) { return __uint_as_float(((u32)v) << 16); }
__device__ __forceinline__ u16 f2bf(float f) {
    u32 u = __float_as_uint(f);
    return (u16)((u + 0x7fffu + ((u >> 16) & 1u)) >> 16);
}
__device__ __forceinline__ float lo16(u32 u) { return __uint_as_float(u << 16); }
__device__ __forceinline__ float hi16(u32 u) { return __uint_as_float(u & 0xffff0000u); }
__device__ __forceinline__ u32 pk(float a, float b) {
    return (u32)f2bf(a) | ((u32)f2bf(b) << 16);
}

// AGPR pinning (validated R6-R8)
__device__ __forceinline__ au4 apin(uint4 v) {
    au4 t; t.x = v.x; t.y = v.y; t.z = v.z; t.w = v.w;
    au4 r;
    asm volatile("" : "=a"(r) : "0"(t));
    return r;
}
__device__ __forceinline__ au4 ageta(au4 a) {
    au4 t;
    asm volatile("" : "=a"(t) : "0"(a));
    return t;
}

template <bool IS32>
__device__ __forceinline__ float ldf(const void* p, int i) {
    return IS32 ? ((const float*)p)[i] : bf2f(((const u16*)p)[i]);
}
template <bool IS32>
__device__ __forceinline__ u16 ldbf(const void* p, int i) {
    return IS32 ? f2bf(((const float*)p)[i]) : ((const u16*)p)[i];
}

__device__ __forceinline__ float rcpf(float x) { return __builtin_amdgcn_rcpf(x); }
__device__ __forceinline__ float lipswish(float x) {
    return 0.909f * x * rcpf(1.0f + __expf(-x));   // inf-safe
}
__device__ __forceinline__ float tanh_fast(float x) {
    float e = __expf(2.0f * fabsf(x));
    float t = 1.0f - 2.0f * rcpf(e + 1.0f);
    return copysignf(t, x);
}
__device__ __forceinline__ void split_bf(float v, u16& hi, u16& lo) {
    hi = f2bf(v);
    lo = f2bf(v - bf2f(hi));
}

struct __align__(16) SMem {
    // activations as MFMA B operands: bf16 hi + lo residual
    __align__(16) u16 bxh[BB][96],  bxl[BB][96];        // x=[t,y,pad]
    __align__(16) u16 bh1h[2][BB][WID], bh1l[2][BB][WID];
    __align__(16) u16 bh2vh[BB][WID], bh2vl[BB][WID];
    __align__(16) u16 bh2ch[BB][WID], bh2cl[BB][WID];
    __align__(16) u16 vW2F[4][4][64][8];                // drift L2, frag-major
    // raw MFMA outputs, 4 columns (0,1 = samples hi; 2,3 = samples lo)
    __align__(16) float accL0[4][256];
    __align__(16) float accL1[4][256];
    __align__(16) float accL2v[4][HDIM];
    __align__(16) float accB[4][HN];
    __align__(16) float b0s[256], b1s[256], vb2[HDIM], vsc[HDIM];
    __align__(16) float cb2[HN], csc[HN];
    __align__(16) float roW[8][HDIM];
    __align__(16) float rob[8];
    __align__(16) float tsb[1028];
    __align__(16) float yb[BB][HDIM], g0b[BB][HDIM], fdt[BB][HDIM];
    __align__(16) float dwb[BB][NZ];
};

__device__ __forceinline__ bf16x8 bfrag(const u16* p) {
    return __builtin_bit_cast(bf16x8, *(const uint4*)p);
}
__device__ __forceinline__ fx4 mf1(au4 a, bf16x8 b, fx4 acc) {
    bf16x8 af = __builtin_bit_cast(bf16x8, ageta(a));
    return __builtin_amdgcn_mfma_f32_16x16x32_bf16(af, b, acc, 0, 0, 0);
}

template <bool IS32>
__device__ __forceinline__ uint4 load8(const void* src, int row, int stride, int k0, int Klim) {
    u16 e[8];
    #pragma unroll
    for (int j = 0; j < 8; ++j) {
        int k = k0 + j;
        e[j] = (k < Klim) ? ldbf<IS32>(src, row * stride + k) : (u16)0;
    }
    uint4 v;
    v.x = (u32)e[0] | ((u32)e[1] << 16);
    v.y = (u32)e[2] | ((u32)e[3] << 16);
    v.z = (u32)e[4] | ((u32)e[5] << 16);
    v.w = (u32)e[6] | ((u32)e[7] << 16);
    return v;
}

template <bool IS32>
__device__ __forceinline__ void stage_dw(SMem& sm, const uint4& d, int q, float sdt) {
    if (IS32) {
        const float* pf = (const float*)&d;
        int f = q * 4;
        #pragma unroll
        for (int k = 0; k < 4; ++k)
            sm.dwb[(f + k) >> 4][(f + k) & 15] = pf[k] * sdt;
    } else {
        int f = q * 8;
        u32 u0 = d.x, u1 = d.y, u2 = d.z, u3 = d.w;
        sm.dwb[(f    ) >> 4][(f    ) & 15] = lo16(u0) * sdt;
        sm.dwb[(f + 1) >> 4][(f + 1) & 15] = hi16(u0) * sdt;
        sm.dwb[(f + 2) >> 4][(f + 2) & 15] = lo16(u1) * sdt;
        sm.dwb[(f + 3) >> 4][(f + 3) & 15] = hi16(u1) * sdt;
        sm.dwb[(f + 4) >> 4][(f + 4) & 15] = lo16(u2) * sdt;
        sm.dwb[(f + 5) >> 4][(f + 5) & 15] = hi16(u2) * sdt;
        sm.dwb[(f + 6) >> 4][(f + 6) & 15] = lo16(u3) * sdt;
        sm.dwb[(f + 7) >> 4][(f + 7) & 15] = hi16(u3) * sdt;
    }
}

template <bool IS32>
__device__ __forceinline__ void write_out(void* out, size_t idx, const float* v8) {
    if (IS32) {
        float4 o0, o1;
        o0.x = v8[0]; o0.y = v8[1]; o0.z = v8[2]; o0.w = v8[3];
        o1.x = v8[4]; o1.y = v8[5]; o1.z = v8[6]; o1.w = v8[7];
        ((float4*)out)[idx * 2]     = o0;
        ((float4*)out)[idx * 2 + 1] = o1;
    } else {
        uint4 o;
        o.x = pk(v8[0], v8[1]);
        o.y = pk(v8[2], v8[3]);
        o.z = pk(v8[4], v8[5]);
        o.w = pk(v8[6], v8[7]);
        ((uint4*)out)[idx] = o;
    }
}

template <bool IS32>
__device__ __forceinline__ void
sde_run(SMem& sm,
        const void* ts,  const void* z0,  const void* dW,
        const void* iW0, const void* ib0, const void* iW1, const void* ib1,
        const void* iW2, const void* ib2,
        const void* vW0, const void* vb0, const void* vW1, const void* vb1,
        const void* vW2, const void* vb2, const void* vsc,
        const void* cW0, const void* cb0, const void* cW1, const void* cb1,
        const void* cW2, const void* cb2, const void* csc,
        const void* roW, const void* rob, void* out,
        int tid, int bid)
{
    const int lane = tid & 63, wv = tid >> 6;
    const int mm = lane & 15, qq = lane >> 4;
    const int nn = mm;                 // B/D column within tile
    const int smp = nn & 1;            // sample this column carries
    const int prt = (nn >> 1) & 1;     // 0 = hi part, 1 = lo part

    // ---- weight A-fragments -> AGPRs (184 u32/thread) ----
    au4 a0[6];    // stacked [vW0;cW0]: rows 16(2wv+rtl)+mm, kt 0..2 (K=65 pad 96)
    au4 a1[8];    // waves0-3 vW1, waves4-7 cW1: rows 16(2(wv&3)+rtl)+mm, kt 0..3
    au4 ab[32];   // cW2: rows 128wv+16r8+mm, kt 0..3
    #pragma unroll
    for (int rtl = 0; rtl < 2; ++rtl) {
        int grow = 16 * (2 * wv + rtl) + mm;
        const void* src = (grow < 128) ? vW0 : cW0;
        int r = grow & 127;
        #pragma unroll
        for (int kt = 0; kt < 3; ++kt)
            a0[rtl * 3 + kt] = apin(load8<IS32>(src, r, IND, 32 * kt + 8 * qq, IND));
    }
    {
        const void* src = (wv < 4) ? vW1 : cW1;
        int wl = wv & 3;
        #pragma unroll
        for (int rtl = 0; rtl < 2; ++rtl) {
            int r = 16 * (2 * wl + rtl) + mm;
            #pragma unroll
            for (int kt = 0; kt < 4; ++kt)
                a1[rtl * 4 + kt] = apin(load8<IS32>(src, r, WID, 32 * kt + 8 * qq, WID));
        }
    }
    #pragma unroll
    for (int r8 = 0; r8 < 8; ++r8) {
        int r = 128 * wv + 16 * r8 + mm;
        #pragma unroll
        for (int kt = 0; kt < 4; ++kt)
            ab[r8 * 4 + kt] = apin(load8<IS32>(cW2, r, WID, 32 * kt + 8 * qq, WID));
    }

    // ---- LDS staging ----
    for (int slot = tid; slot < 1024; slot += NTHREADS) {
        int rt = slot >> 8, kt = (slot >> 6) & 3, l = slot & 63;
        int m = l & 15, q = l >> 4;
        uint4 v = load8<IS32>(vW2, 16 * rt + m, WID, 32 * kt + 8 * q, WID);
        *(uint4*)&sm.vW2F[rt][kt][l][0] = v;
    }
    if (tid < 256) {
        sm.b0s[tid] = (tid < 128) ? ldf<IS32>(vb0, tid) : ldf<IS32>(cb0, tid - 128);
        sm.b1s[tid] = (tid < 128) ? ldf<IS32>(vb1, tid) : ldf<IS32>(cb1, tid - 128);
    } else if (tid < 320) {
        int i = tid - 256;
        sm.vb2[i] = ldf<IS32>(vb2, i);
        sm.vsc[i] = ldf<IS32>(vsc, i);
    } else if (tid < 328) {
        sm.rob[tid - 320] = ldf<IS32>(rob, tid - 320);
    } else if (tid >= 384 && tid < 448) {
        int b = (tid - 384) >> 5, k = 65 + ((tid - 384) & 31);
        if (k < 96) { sm.bxh[b][k] = 0; sm.bxl[b][k] = 0; }
    }
    for (int i = tid; i < HN; i += NTHREADS) {
        sm.cb2[i] = ldf<IS32>(cb2, i);
        sm.csc[i] = ldf<IS32>(csc, i);
    }
    { int d = tid >> 6, i2 = tid & 63; sm.roW[d][i2] = ldf<IS32>(roW, tid); }
    for (int i = tid; i < TPTS; i += NTHREADS) sm.tsb[i] = ldf<IS32>(ts, i);

    uint4 dwpref;
    if (tid >= 128 && tid < 136) {
        int q = tid - 128;
        if (IS32)       dwpref = ((const uint4*)dW)[(size_t)bid * 8 + q];
        else if (q < 4) dwpref = ((const uint4*)dW)[(size_t)bid * 4 + q];
    }
    __syncthreads();

    const float dt  = sm.tsb[1] - sm.tsb[0];
    const float sdt = sqrtf(dt);
    if (tid >= 128 && tid < 136) {
        int q = tid - 128;
        if (IS32 || q < 4) stage_dw<IS32>(sm, dwpref, q, sdt);
    }

    // ---- initial MLP (VALU, once): z0 -> 128 -> 128 -> y0; scratch accB[0..1] ----
    if (tid < 256) {
        int b = tid >> 7, j = tid & 127;
        float acc = ldf<IS32>(ib0, j);
        #pragma unroll
        for (int k = 0; k < 8; ++k)
            acc = fmaf(ldf<IS32>(iW0, j * 8 + k), ldf<IS32>(z0, (bid * BB + b) * 8 + k), acc);
        sm.accB[0][b * 128 + j] = fmaxf(acc, 0.0f);
    }
    __syncthreads();
    if (tid < 256) {
        int b = tid >> 7, j = tid & 127;
        float acc = ldf<IS32>(ib1, j);
        for (int k = 0; k < WID; ++k)
            acc = fmaf(ldf<IS32>(iW1, j * WID + k), sm.accB[0][b * 128 + k], acc);
        sm.accB[1][b * 128 + j] = fmaxf(acc, 0.0f);
    }
    __syncthreads();
    if (tid < 128) {
        int b = tid >> 6, i = tid & 63;
        float y0 = ldf<IS32>(ib2, i);
        for (int k = 0; k < WID; ++k)
            y0 = fmaf(ldf<IS32>(iW2, i * WID + k), sm.accB[1][b * 128 + k], y0);
        sm.yb[b][i] = y0;
        u16 hi, lo; split_bf(y0, hi, lo);
        sm.bxh[b][1 + i] = hi; sm.bxl[b][1 + i] = lo;
        if (i == 0) {
            u16 thi, tlo; split_bf(sm.tsb[0], thi, tlo);
            sm.bxh[b][0] = thi; sm.bxl[b][0] = tlo;
        }
    }
    __syncthreads();

    // ---- main scan: 12 barriers/step (R8 structure), column-folded MFMA ----
    for (int s = 0; s < STEPS; ++s) {
        // PA: L0 both MLPs on x (all waves) -> raw accL0 cols 0-3; stage dwb (s>0)
        if (s > 0 && tid >= 128 && tid < 136) {
            int q = tid - 128;
            if (IS32 || q < 4) stage_dw<IS32>(sm, dwpref, q, sdt);
        }
        {
            const u16* xs = prt ? &sm.bxl[smp][0] : &sm.bxh[smp][0];
            bf16x8 bx[3];
            #pragma unroll
            for (int kt = 0; kt < 3; ++kt) bx[kt] = bfrag(&xs[32 * kt + 8 * qq]);
            #pragma unroll
            for (int rtl = 0; rtl < 2; ++rtl) {
                fx4 acc = {0.f, 0.f, 0.f, 0.f};
                #pragma unroll
                for (int kt = 0; kt < 3; ++kt) acc = mf1(a0[rtl * 3 + kt], bx[kt], acc);
                int rowb = 16 * (2 * wv + rtl) + 4 * qq;
                if (nn < 4) *(fx4*)&sm.accL0[nn][rowb] = acc;
            }
        }
        __syncthreads();
        // PB: act L0 (512 thr): fold hi+lo cols -> bh1
        {
            int r = tid >> 1, c = tid & 1;
            float h = lipswish(sm.accL0[c][r] + sm.accL0[c + 2][r] + sm.b0s[r]);
            u16 hi, lo; split_bf(h, hi, lo);
            int mlp = r >> 7, j = r & 127;
            sm.bh1h[mlp][c][j] = hi;
            sm.bh1l[mlp][c][j] = lo;
        }
        __syncthreads();
        // PC: L1 MFMA (waves0-3 drift, 4-7 diffusion) -> raw accL1
        {
            int mlp = (wv < 4) ? 0 : 1, wl = wv & 3;
            const u16* hs = prt ? &sm.bh1l[mlp][smp][0] : &sm.bh1h[mlp][smp][0];
            bf16x8 bf[4];
            #pragma unroll
            for (int kt = 0; kt < 4; ++kt) bf[kt] = bfrag(&hs[32 * kt + 8 * qq]);
            #pragma unroll
            for (int rtl = 0; rtl < 2; ++rtl) {
                fx4 acc = {0.f, 0.f, 0.f, 0.f};
                #pragma unroll
                for (int kt = 0; kt < 4; ++kt) acc = mf1(a1[rtl * 4 + kt], bf[kt], acc);
                int rowb = mlp * 128 + 16 * (2 * wl + rtl) + 4 * qq;
                if (nn < 4) *(fx4*)&sm.accL1[nn][rowb] = acc;
            }
        }
        __syncthreads();
        // PD: act L1 (512 thr) -> bh2v / bh2c
        {
            int r = tid >> 1, c = tid & 1;
            float h = lipswish(sm.accL1[c][r] + sm.accL1[c + 2][r] + sm.b1s[r]);
            u16 hi, lo; split_bf(h, hi, lo);
            if (r < 128) { sm.bh2vh[c][r] = hi;       sm.bh2vl[c][r] = lo; }
            else         { sm.bh2ch[c][r - 128] = hi; sm.bh2cl[c][r - 128] = lo; }
        }
        __syncthreads();
        // PE: big MFMA eval1 (all waves) -> accB; drift L2 (waves 0-3) -> accL2v
        {
            const u16* cs2 = prt ? &sm.bh2cl[smp][0] : &sm.bh2ch[smp][0];
            bf16x8 bc[4];
            #pragma unroll
            for (int kt = 0; kt < 4; ++kt) bc[kt] = bfrag(&cs2[32 * kt + 8 * qq]);
            #pragma unroll
            for (int r8 = 0; r8 < 8; ++r8) {
                fx4 acc = {0.f, 0.f, 0.f, 0.f};
                #pragma unroll
                for (int kt = 0; kt < 4; ++kt) acc = mf1(ab[r8 * 4 + kt], bc[kt], acc);
                int rowb = 128 * wv + 16 * r8 + 4 * qq;
                if (nn < 4) *(fx4*)&sm.accB[nn][rowb] = acc;
            }
            if (wv < 4) {
                const u16* vs2 = prt ? &sm.bh2vl[smp][0] : &sm.bh2vh[smp][0];
                fx4 acc = {0.f, 0.f, 0.f, 0.f};
                #pragma unroll
                for (int kt = 0; kt < 4; ++kt) {
                    bf16x8 aw = bfrag(&sm.vW2F[wv][kt][lane][0]);
                    acc = __builtin_amdgcn_mfma_f32_16x16x32_bf16(aw, bfrag(&vs2[32 * kt + 8 * qq]), acc, 0, 0, 0);
                }
                int i0 = 16 * wv + 4 * qq;
                if (nn < 4) *(fx4*)&sm.accL2v[nn][i0] = acc;
            }
        }
        __syncthreads();
        // PF: epilogue 1 (512 thr): g0 fold; fdt (tid<128); x' pack
        {
            int b = tid >> 8, h = (tid >> 2) & 63, q4 = tid & 3;
            int rb = 16 * h + 4 * q4;
            fx4 aH = *(const fx4*)&sm.accB[b][rb];
            fx4 aL = *(const fx4*)&sm.accB[b + 2][rb];
            float4 cb = *(const float4*)&sm.cb2[rb];
            float4 cs = *(const float4*)&sm.csc[rb];
            float4 dw = *(const float4*)&sm.dwb[b][4 * q4];
            float v;
            v  = tanh_fast(aH.x + aL.x + cb.x) * cs.x * dw.x;
            v  = fmaf(tanh_fast(aH.y + aL.y + cb.y) * cs.y, dw.y, v);
            v  = fmaf(tanh_fast(aH.z + aL.z + cb.z) * cs.z, dw.z, v);
            v  = fmaf(tanh_fast(aH.w + aL.w + cb.w) * cs.w, dw.w, v);
            v += __shfl_xor(v, 1);
            v += __shfl_xor(v, 2);
            if (tid < 128) {
                int b2 = tid >> 6, i = tid & 63;
                sm.fdt[b2][i] = sm.vsc[i] * tanh_fast(sm.accL2v[b2][i] + sm.accL2v[b2 + 2][i] + sm.vb2[i]) * dt;
            }
            if (q4 == 0) {
                sm.g0b[b][h] = v;
                float xp = sm.yb[b][h] + v;
                u16 hi, lo; split_bf(xp, hi, lo);
                sm.bxh[b][1 + h] = hi; sm.bxl[b][1 + h] = lo;
            }
        }
        __syncthreads();
        // PA2: diffusion L0 on x' (waves 4-7) | readout y_s (tid<128) | dW prefetch
        if (wv >= 4) {
            const u16* xs = prt ? &sm.bxl[smp][0] : &sm.bxh[smp][0];
            bf16x8 bx[3];
            #pragma unroll
            for (int kt = 0; kt < 3; ++kt) bx[kt] = bfrag(&xs[32 * kt + 8 * qq]);
            #pragma unroll
            for (int rtl = 0; rtl < 2; ++rtl) {
                fx4 acc = {0.f, 0.f, 0.f, 0.f};
                #pragma unroll
                for (int kt = 0; kt < 3; ++kt) acc = mf1(a0[rtl * 3 + kt], bx[kt], acc);
                int rowb = 16 * (2 * wv + rtl) + 4 * qq;   // 128..255
                if (nn < 4) *(fx4*)&sm.accL0[nn][rowb] = acc;
            }
        } else if (tid < 128) {
            int b = tid >> 6, i = tid & 63;
            float y = sm.yb[b][i];
            float acc8[8];
            #pragma unroll
            for (int d = 0; d < 8; ++d) acc8[d] = sm.roW[d][i] * y;
            #pragma unroll
            for (int m = 1; m < 64; m <<= 1) {
                #pragma unroll
                for (int d = 0; d < 8; ++d) acc8[d] += __shfl_xor(acc8[d], m);
            }
            if (i == 0) {
                float v8[8];
                #pragma unroll
                for (int d = 0; d < 8; ++d) v8[d] = acc8[d] + sm.rob[d];
                write_out<IS32>(out, (size_t)(bid * BB + b) * TPTS + s, v8);
            }
        } else if (tid >= 128 && tid < 136 && s + 1 < STEPS) {
            int q = tid - 128;
            if (IS32)       dwpref = ((const uint4*)dW)[(size_t)(s + 1) * 2048 + bid * 8 + q];
            else if (q < 4) dwpref = ((const uint4*)dW)[(size_t)(s + 1) * 1024 + bid * 4 + q];
        }
        __syncthreads();
        // PB2: act diffusion L0 (256 thr)
        if (tid < 256) {
            int r = 128 + (tid >> 1), c = tid & 1;
            float h = lipswish(sm.accL0[c][r] + sm.accL0[c + 2][r] + sm.b0s[r]);
            u16 hi, lo; split_bf(h, hi, lo);
            sm.bh1h[1][c][r - 128] = hi;
            sm.bh1l[1][c][r - 128] = lo;
        }
        __syncthreads();
        // PC2: diffusion L1 MFMA (waves 4-7)
        if (wv >= 4) {
            int wl = wv & 3;
            const u16* hs = prt ? &sm.bh1l[1][smp][0] : &sm.bh1h[1][smp][0];
            bf16x8 bf[4];
            #pragma unroll
            for (int kt = 0; kt < 4; ++kt) bf[kt] = bfrag(&hs[32 * kt + 8 * qq]);
            #pragma unroll
            for (int rtl = 0; rtl < 2; ++rtl) {
                fx4 acc = {0.f, 0.f, 0.f, 0.f};
                #pragma unroll
                for (int kt = 0; kt < 4; ++kt) acc = mf1(a1[rtl * 4 + kt], bf[kt], acc);
                int rowb = 128 + 16 * (2 * wl + rtl) + 4 * qq;
                if (nn < 4) *(fx4*)&sm.accL1[nn][rowb] = acc;
            }
        }
        __syncthreads();
        // PD2: act diffusion L1 (256 thr)
        if (tid < 256) {
            int r = 128 + (tid >> 1), c = tid & 1;
            float h = lipswish(sm.accL1[c][r] + sm.accL1[c + 2][r] + sm.b1s[r]);
            u16 hi, lo; split_bf(h, hi, lo);
            sm.bh2ch[c][r - 128] = hi;
            sm.bh2cl[c][r - 128] = lo;
        }
        __syncthreads();
        // PE2: big MFMA eval2 (all waves) -> accB
        {
            const u16* cs2 = prt ? &sm.bh2cl[smp][0] : &sm.bh2ch[smp][0];
            bf16x8 bc[4];
            #pragma unroll
            for (int kt = 0; kt < 4; ++kt) bc[kt] = bfrag(&cs2[32 * kt + 8 * qq]);
            #pragma unroll
            for (int r8 = 0; r8 < 8; ++r8) {
                fx4 acc = {0.f, 0.f, 0.f, 0.f};
                #pragma unroll
                for (int kt = 0; kt < 4; ++kt) acc = mf1(ab[r8 * 4 + kt], bc[kt], acc);
                int rowb = 128 * wv + 16 * r8 + 4 * qq;
                if (nn < 4) *(fx4*)&sm.accB[nn][rowb] = acc;
            }
        }
        __syncthreads();
        // PF2: epilogue 2 (512 thr): g1 fold; y1 update + next-x pack + t
        {
            int b = tid >> 8, h = (tid >> 2) & 63, q4 = tid & 3;
            int rb = 16 * h + 4 * q4;
            fx4 aH = *(const fx4*)&sm.accB[b][rb];
            fx4 aL = *(const fx4*)&sm.accB[b + 2][rb];
            float4 cb = *(const float4*)&sm.cb2[rb];
            float4 cs = *(const float4*)&sm.csc[rb];
            float4 dw = *(const float4*)&sm.dwb[b][4 * q4];
            float v;
            v  = tanh_fast(aH.x + aL.x + cb.x) * cs.x * dw.x;
            v  = fmaf(tanh_fast(aH.y + aL.y + cb.y) * cs.y, dw.y, v);
            v  = fmaf(tanh_fast(aH.z + aL.z + cb.z) * cs.z, dw.z, v);
            v  = fmaf(tanh_fast(aH.w + aL.w + cb.w) * cs.w, dw.w, v);
            v += __shfl_xor(v, 1);
            v += __shfl_xor(v, 2);
            if (q4 == 0) {
                float y1 = sm.yb[b][h] + sm.fdt[b][h] + 0.5f * (sm.g0b[b][h] + v);
                sm.yb[b][h] = y1;
                u16 hi, lo; split_bf(y1, hi, lo);
                sm.bxh[b][1 + h] = hi; sm.bxl[b][1 + h] = lo;
                if (h == 0) {
                    u16 thi, tlo; split_bf(sm.tsb[s + 1], thi, tlo);
                    sm.bxh[b][0] = thi; sm.bxl[b][0] = tlo;
                }
            }
        }
        __syncthreads();
    }

    // final readout: y_1024
    if (tid < 128) {
        int b = tid >> 6, i = tid & 63;
        float y = sm.yb[b][i];
        float acc8[8];
        #pragma unroll
        for (int d = 0; d < 8; ++d) acc8[d] = sm.roW[d][i] * y;
        #pragma unroll
        for (int m = 1; m < 64; m <<= 1) {
            #pragma unroll
            for (int d = 0; d < 8; ++d) acc8[d] += __shfl_xor(acc8[d], m);
        }
        if (i == 0) {
            float v8[8];
            #pragma unroll
            for (int d = 0; d < 8; ++d) v8[d] = acc8[d] + sm.rob[d];
            write_out<IS32>(out, (size_t)(bid * BB + b) * TPTS + STEPS, v8);
        }
    }
}

__global__ void
__attribute__((amdgpu_flat_work_group_size(NTHREADS, NTHREADS), amdgpu_waves_per_eu(2, 2)))
sde_kernel(const void* __restrict__ ts,  const void* __restrict__ z0,  const void* __restrict__ dW,
           const void* __restrict__ iW0, const void* __restrict__ ib0, const void* __restrict__ iW1,
           const void* __restrict__ ib1, const void* __restrict__ iW2, const void* __restrict__ ib2,
           const void* __restrict__ vW0, const void* __restrict__ vb0, const void* __restrict__ vW1,
           const void* __restrict__ vb1, const void* __restrict__ vW2, const void* __restrict__ vb2,
           const void* __restrict__ vsc, const void* __restrict__ cW0, const void* __restrict__ cb0,
           const void* __restrict__ cW1, const void* __restrict__ cb1, const void* __restrict__ cW2,
           const void* __restrict__ cb2, const void* __restrict__ csc, const void* __restrict__ roW,
           const void* __restrict__ rob, void* __restrict__ out)
{
    __shared__ SMem sm;
    const int tid = threadIdx.x;
    const int bid = blockIdx.x;

    // dtype detection: u16 word #1 of ts (bf16 -> 0x3A80 != 0; fp32 -> 0)
    const bool is32 = (((const u16*)ts)[1] == 0);

    if (is32) {
        sde_run<true>(sm, ts, z0, dW, iW0, ib0, iW1, ib1, iW2, ib2,
                      vW0, vb0, vW1, vb1, vW2, vb2, vsc,
                      cW0, cb0, cW1, cb1, cW2, cb2, csc, roW, rob, out, tid, bid);
    } else {
        sde_run<false>(sm, ts, z0, dW, iW0, ib0, iW1, ib1, iW2, ib2,
                       vW0, vb0, vW1, vb1, vW2, vb2, vsc,
                       cW0, cb0, cW1, cb1, cW2, cb2, csc, roW, rob, out, tid, bid);
    }
}

extern "C" void kernel_launch(void* const* d_in, const int* in_sizes, int n_in,
                              void* d_out, int out_size, void* d_ws, size_t ws_size,
                              hipStream_t stream) {
    (void)in_sizes; (void)n_in; (void)d_ws; (void)ws_size; (void)out_size;
    hipLaunchKernelGGL(sde_kernel, dim3(NBLOCKS), dim3(NTHREADS), 0, stream,
                       d_in[0], d_in[1], d_in[2], d_in[3], d_in[4], d_in[5], d_in[6],
                       d_in[7], d_in[8], d_in[9], d_in[10], d_in[11], d_in[12], d_in[13],
                       d_in[14], d_in[15], d_in[16], d_in[17], d_in[18], d_in[19], d_in[20],
                       d_in[21], d_in[22], d_in[23], d_in[24], d_out);
}